// Round 3
// baseline (453.761 us; speedup 1.0000x reference)
//
#include <hip/hip_runtime.h>
#include <math.h>

#define DD 64
#define LL 2048
#define HEADS 32
#define TQ 128
#define TK 64
#define NTHREADS 512
// 1/sqrt(64) * log2(e), folded into Q at staging (leaky commutes with positive scale)
#define QSCALE 0.18033688011112042f

typedef __bf16 bf16_t;
typedef __bf16 bf16x8 __attribute__((ext_vector_type(8)));
typedef float f32x16 __attribute__((ext_vector_type(16)));

// ============================================================================
// Prepass (K,V only — Q has no cross-block reuse, main kernel stages it):
//   z=0: KT[head][l][d] = k[head][d][l]   (transposed, bf16)
//   z=1: VB[head][d][l] = v[head][d][l]   (straight convert, bf16)
// ~33.5 MB read + 16.8 MB write => ~8 us memory-bound.
// ============================================================================
__global__ __launch_bounds__(256)
void prep_bf16_kv(const float* __restrict__ k, const float* __restrict__ v,
                  bf16_t* __restrict__ kt, bf16_t* __restrict__ vb) {
  __shared__ float ld[64][65];
  const int t = threadIdx.x;
  const int which = blockIdx.z;
  const int head = blockIdx.y;
  const int l0 = blockIdx.x * 64;
  const size_t hoff = (size_t)head * DD * LL;
  if (which == 1) {
    // V: no transpose; float2 read (coalesced), packed 4B bf16x2 write
    const float* src = v + hoff;
    bf16_t* dst = vb + hoff;
    const int lp = (t & 31) * 2;
    const int db = (t >> 5) * 8;
    for (int i = 0; i < 8; ++i) {
      int d = db + i;
      float2 x = *(const float2*)(src + (size_t)d * LL + l0 + lp);
      union { bf16_t b[2]; unsigned u; } pk;
      pk.b[0] = (bf16_t)x.x;
      pk.b[1] = (bf16_t)x.y;
      *(unsigned*)(dst + (size_t)d * LL + l0 + lp) = pk.u;
    }
  } else {
    // K: 64x64 tile transpose through LDS (pad 65: conflict-free)
    const float* src = k + hoff;
    bf16_t* dst = kt + hoff;
    const int l = t & 63;
    const int db = (t >> 6) * 16;
    for (int i = 0; i < 16; ++i) {
      int d = db + i;
      ld[l][d] = src[(size_t)d * LL + l0 + l];  // coalesced along l
    }
    __syncthreads();
    const int dp = (t & 31) * 2;
    const int lb = (t >> 5) * 8;
    for (int i = 0; i < 8; ++i) {
      int lw = lb + i;
      union { bf16_t b[2]; unsigned u; } pk;
      pk.b[0] = (bf16_t)ld[lw][dp];
      pk.b[1] = (bf16_t)ld[lw][dp + 1];
      *(unsigned*)(dst + (size_t)(l0 + lw) * DD + dp) = pk.u;  // coalesced along d
    }
  }
}

// ============================================================================
// Main kernel v4: v2 structure (TQ=128, 512 thr / 8 waves) with:
//  - Qs UNIONED into the Ks double-buffer (Q dead after reg hoist; one extra
//    barrier) => LDS 55.8 -> 37.4 KB => 4 blocks/CU (32 waves/CU).
//  - XCD-aware 1D grid: bid%8 == head%8, so one head's 16 q-tiles share an
//    XCD; 4 heads x 512KB K/V = 2MB resident in that XCD's 4MB L2.
//  - Q staged from fp32 in-kernel (prepass is K/V only).
//  - rsum split into 4 accumulators (was a serial 16-deep fp-add chain).
// ============================================================================
struct __align__(16) SMemA4 {
  union {
    bf16_t Qs[TQ][72];       // [lq][d] pre-scaled bf16 (dead after bq hoist)
    bf16_t Ks[2][TK][72];    // double-buffered [lk][d]
  } qk;
  bf16_t Vs[2][DD][72];      // double-buffered [d][lk]
};
union __align__(16) SMemU4 {
  SMemA4 a;
  float Oe[TQ][65];          // epilogue combine/transpose buffer (33.3 KB)
};

__global__ __launch_bounds__(NTHREADS, 8)
void attn_flash_bf16_v4(const float* __restrict__ q, const bf16_t* __restrict__ kt,
                        const bf16_t* __restrict__ vb, float* __restrict__ out) {
  __shared__ SMemU4 sm;
  __shared__ float rs1[TQ];
  const int tid  = threadIdx.x;
  const int w    = tid >> 6;        // wave 0..7
  const int lane = tid & 63;
  const int l31  = lane & 31;
  const int hh   = lane >> 5;       // half of wave
  const int strip = w & 3;          // lq strip 0..3
  const int half  = w >> 2;         // lk half 0/1
  const int wbase = strip * 32;
  const int lkh   = half * 32;
  // ---- XCD-aware decode: bid%8 pins head%8 => per-XCD L2-resident K/V ----
  const int bid  = blockIdx.x;
  const int j    = bid >> 3;
  const int head = (bid & 7) + 8 * (j >> 4);
  const int q0   = (j & 15) * TQ;
  const size_t hoff = (size_t)head * DD * LL;
  const float*  qp = q  + hoff;
  const bf16_t* kp = kt + hoff;
  const bf16_t* vp = vb + hoff;

  // staging coords: K transpose rows + V natural rows, 16B per thread each
  const int srow = tid >> 3;        // 0..63 (lk for K, d for V)
  const int scol = (tid & 7) * 8;

  // ---- prefetch tile 0 (in flight under Q staging) ----
  bf16x8 kreg = *(const bf16x8*)(kp + (size_t)srow * DD + scol);
  bf16x8 vreg = *(const bf16x8*)(vp + (size_t)srow * LL + scol);

  // ---- stage Q transposed from fp32: lanes along lq => coalesced 512B lines ----
  {
    int lq  = tid & 127;
    int d0q = (tid >> 7) * 16;
    const float* src = qp + q0 + lq;
    for (int g = 0; g < 2; ++g) {
      bf16x8 pk;
      for (int jj = 0; jj < 8; ++jj)
        pk[jj] = (bf16_t)(src[(size_t)(d0q + g * 8 + jj) * LL] * QSCALE);
      *(bf16x8*)&sm.a.qk.Qs[lq][d0q + g * 8] = pk;
    }
  }

  __syncthreads();   // Q staged
  bf16x8 bq[4];
  for (int kk = 0; kk < 4; ++kk)
    bq[kk] = *(const bf16x8*)&sm.a.qk.Qs[wbase + l31][kk * 16 + 8 * hh];
  __syncthreads();   // ALL waves done reading Qs; aliased Ks writes now safe

  f32x16 oacc[2];
  for (int dt = 0; dt < 2; ++dt)
    for (int r = 0; r < 16; ++r) oacc[dt][r] = 0.f;
  float rsl[4];
  for (int i = 0; i < 4; ++i) rsl[i] = 0.f;

  for (int t = 0; t < LL / TK; ++t) {
    const int cur = t & 1;
    // ---- commit prefetched tile into buffer `cur` (race-free single barrier:
    //      prior readers of buf[cur] were at iter t-2, separated by t-1 barrier) ----
    *(bf16x8*)&sm.a.qk.Ks[cur][srow][scol] = kreg;
    *(bf16x8*)&sm.a.Vs[cur][srow][scol]    = vreg;
    __syncthreads();

    // ---- issue prefetch for tile t+1 (in flight during compute) ----
    if (t + 1 < LL / TK) {
      const int lk0n = (t + 1) * TK;
      kreg = *(const bf16x8*)(kp + (size_t)(lk0n + srow) * DD + scol);
      vreg = *(const bf16x8*)(vp + (size_t)srow * LL + lk0n + scol);
    }

    // ---- S^T = K^T Q over this wave's lk half: C col=lq(lane), rows=lk(regs) ----
    f32x16 st;
    for (int r = 0; r < 16; ++r) st[r] = 0.f;
    __builtin_amdgcn_s_setprio(1);
    for (int kk = 0; kk < 4; ++kk) {
      bf16x8 ak = *(const bf16x8*)&sm.a.qk.Ks[cur][lkh + l31][kk * 16 + 8 * hh];
      st = __builtin_amdgcn_mfma_f32_32x32x16_bf16(ak, bq[kk], st, 0, 0, 0);
    }
    __builtin_amdgcn_s_setprio(0);

    // ---- leaky + exp2 in registers (4-way split sum: no serial add chain) ----
    unsigned pb[8];
#pragma unroll
    for (int r = 0; r < 16; ++r) {
      float s = st[r];
      s = fmaxf(s, 0.01f * s);
      float p = __builtin_amdgcn_exp2f(s);
      rsl[r & 3] += p;
      st[r] = p;
    }
    for (int qq = 0; qq < 8; ++qq) {
      union { bf16_t b[2]; unsigned u; } pk;
      pk.b[0] = (bf16_t)st[2 * qq];
      pk.b[1] = (bf16_t)st[2 * qq + 1];
      pb[qq] = pk.u;
    }

    // ---- PV over this wave's lk half: one cross-half exchange ----
    for (int kk2 = 0; kk2 < 2; ++kk2) {
      unsigned l0 = pb[4 * kk2 + 0], l1 = pb[4 * kk2 + 1];
      unsigned l2 = pb[4 * kk2 + 2], l3 = pb[4 * kk2 + 3];
      unsigned s0 = hh ? l0 : l2;
      unsigned s1 = hh ? l1 : l3;
      unsigned f0 = (unsigned)__shfl_xor((int)s0, 32);
      unsigned f1 = (unsigned)__shfl_xor((int)s1, 32);
      union { unsigned u[4]; bf16x8 v; } ap;
      ap.u[0] = hh ? f0 : l0;
      ap.u[1] = hh ? f1 : l1;
      ap.u[2] = hh ? l2 : f0;
      ap.u[3] = hh ? l3 : f1;
      const int lkb = lkh + kk2 * 16 + 8 * hh;
      __builtin_amdgcn_s_setprio(1);
      for (int dt = 0; dt < 2; ++dt) {
        bf16x8 bv = *(const bf16x8*)&sm.a.Vs[cur][dt * 32 + l31][lkb];
        oacc[dt] = __builtin_amdgcn_mfma_f32_32x32x16_bf16(ap.v, bv, oacc[dt], 0, 0, 0);
      }
      __builtin_amdgcn_s_setprio(0);
    }
  }

  // ---- epilogue: combine lk-half pairs, normalize, transpose, store ----
  float rsum = (rsl[0] + rsl[1]) + (rsl[2] + rsl[3]);
  float rtot = rsum + __shfl_xor(rsum, 32);   // both hh row-groups of this wave
  __syncthreads();                            // all compute LDS reads done; union safe
  if (half == 1) {
    rs1[wbase + l31] = rtot;
    for (int r = 0; r < 16; ++r) {
      int row = (r & 3) + 8 * (r >> 2) + 4 * hh;
      for (int dt = 0; dt < 2; ++dt)
        sm.Oe[wbase + row][dt * 32 + l31] = oacc[dt][r];
    }
  }
  __syncthreads();
  if (half == 0) {
    float tot = rtot + rs1[wbase + l31];
    rs1[wbase + l31] = 1.0f / tot;            // same-lane read-then-write: safe in-wave
    float inv[16];
    for (int r = 0; r < 16; ++r) {
      int row = (r & 3) + 8 * (r >> 2) + 4 * hh;
      inv[r] = rs1[wbase + row];              // in-wave broadcast reads
    }
    for (int r = 0; r < 16; ++r) {
      int row = (r & 3) + 8 * (r >> 2) + 4 * hh;
      for (int dt = 0; dt < 2; ++dt) {
        int col = dt * 32 + l31;
        sm.Oe[wbase + row][col] = (oacc[dt][r] + sm.Oe[wbase + row][col]) * inv[r];
      }
    }
  }
  __syncthreads();
  float* op = out + hoff + q0;
  for (int i = 0; i < 16; ++i) {
    int idx = tid + NTHREADS * i;  // 0..8191
    int d   = idx >> 7;
    int lq  = idx & 127;
    op[(size_t)d * LL + lq] = sm.Oe[lq][d];   // coalesced: lanes -> consecutive lq
  }
}

// ============================================================================
// Fallback: the original harness-verified fp32-input kernel, used only if
// ws_size is too small for the bf16 prepass buffers.
// ============================================================================
struct __align__(16) SMemA {
  bf16_t Qs[TQ][72];
  bf16_t Ks[TK][72];
  bf16_t Vs[DD][72];
};
union __align__(16) SMemU {
  SMemA a;
  float Oe[TQ][65];
};

__global__ __launch_bounds__(NTHREADS, 4)
void attn_flash_bf16(const float* __restrict__ q, const float* __restrict__ k,
                     const float* __restrict__ v, float* __restrict__ out) {
  __shared__ SMemU sm;
  __shared__ float rs1[TQ];
  const int tid  = threadIdx.x;
  const int w    = tid >> 6;
  const int lane = tid & 63;
  const int l31  = lane & 31;
  const int hh   = lane >> 5;
  const int strip = w & 3;
  const int half  = w >> 2;
  const int wbase = strip * 32;
  const int lkh   = half * 32;
  const int head = blockIdx.y;
  const int q0   = blockIdx.x * TQ;
  const size_t hoff = (size_t)head * DD * LL;
  const float* qp = q + hoff;
  const float* kp = k + hoff;
  const float* vp = v + hoff;

  {
    int lq  = tid & 127;
    int d0q = (tid >> 7) * 16;
    const float* src = qp + q0 + lq;
    for (int g = 0; g < 2; ++g) {
      bf16x8 pk;
      for (int jj = 0; jj < 8; ++jj)
        pk[jj] = (bf16_t)(src[(size_t)(d0q + g * 8 + jj) * LL] * QSCALE);
      *(bf16x8*)&sm.a.Qs[lq][d0q + g * 8] = pk;
    }
  }

  const int klk = tid & 63;
  const int kd0 = (tid >> 6) * 8;
  const int vd  = tid >> 3;
  const int vc8 = (tid & 7) * 8;

  float  kreg[8];
  float4 vreg[2];
  {
    const float* ks = kp + klk;
    for (int jj = 0; jj < 8; ++jj) kreg[jj] = ks[(size_t)(kd0 + jj) * LL];
    vreg[0] = *(const float4*)(vp + (size_t)vd * LL + vc8);
    vreg[1] = *(const float4*)(vp + (size_t)vd * LL + vc8 + 4);
  }

  __syncthreads();
  bf16x8 bq[4];
  for (int kk = 0; kk < 4; ++kk)
    bq[kk] = *(const bf16x8*)&sm.a.Qs[wbase + l31][kk * 16 + 8 * hh];

  f32x16 oacc[2];
  for (int dt = 0; dt < 2; ++dt)
    for (int r = 0; r < 16; ++r) oacc[dt][r] = 0.f;
  float rsum = 0.f;

  for (int t = 0; t < LL / TK; ++t) {
    __syncthreads();
    {
      bf16x8 pk;
      for (int jj = 0; jj < 8; ++jj) pk[jj] = (bf16_t)kreg[jj];
      *(bf16x8*)&sm.a.Ks[klk][kd0] = pk;
      bf16x8 pv;
      pv[0] = (bf16_t)vreg[0].x; pv[1] = (bf16_t)vreg[0].y;
      pv[2] = (bf16_t)vreg[0].z; pv[3] = (bf16_t)vreg[0].w;
      pv[4] = (bf16_t)vreg[1].x; pv[5] = (bf16_t)vreg[1].y;
      pv[6] = (bf16_t)vreg[1].z; pv[7] = (bf16_t)vreg[1].w;
      *(bf16x8*)&sm.a.Vs[vd][vc8] = pv;
    }
    __syncthreads();

    if (t + 1 < LL / TK) {
      const int lk0n = (t + 1) * TK;
      const float* ks = kp + lk0n + klk;
      for (int jj = 0; jj < 8; ++jj) kreg[jj] = ks[(size_t)(kd0 + jj) * LL];
      vreg[0] = *(const float4*)(vp + (size_t)vd * LL + lk0n + vc8);
      vreg[1] = *(const float4*)(vp + (size_t)vd * LL + lk0n + vc8 + 4);
    }

    f32x16 st;
    for (int r = 0; r < 16; ++r) st[r] = 0.f;
    for (int kk = 0; kk < 4; ++kk) {
      bf16x8 ak = *(const bf16x8*)&sm.a.Ks[lkh + l31][kk * 16 + 8 * hh];
      st = __builtin_amdgcn_mfma_f32_32x32x16_bf16(ak, bq[kk], st, 0, 0, 0);
    }

    unsigned pb[8];
    for (int r = 0; r < 16; ++r) {
      float s = st[r];
      s = fmaxf(s, 0.01f * s);
      float p = __builtin_amdgcn_exp2f(s);
      rsum += p;
      st[r] = p;
    }
    for (int qq = 0; qq < 8; ++qq) {
      union { bf16_t b[2]; unsigned u; } pk;
      pk.b[0] = (bf16_t)st[2 * qq];
      pk.b[1] = (bf16_t)st[2 * qq + 1];
      pb[qq] = pk.u;
    }

    for (int kk2 = 0; kk2 < 2; ++kk2) {
      unsigned l0 = pb[4 * kk2 + 0], l1 = pb[4 * kk2 + 1];
      unsigned l2 = pb[4 * kk2 + 2], l3 = pb[4 * kk2 + 3];
      unsigned s0 = hh ? l0 : l2;
      unsigned s1 = hh ? l1 : l3;
      unsigned f0 = (unsigned)__shfl_xor((int)s0, 32);
      unsigned f1 = (unsigned)__shfl_xor((int)s1, 32);
      union { unsigned u[4]; bf16x8 v; } ap;
      ap.u[0] = hh ? f0 : l0;
      ap.u[1] = hh ? f1 : l1;
      ap.u[2] = hh ? l2 : f0;
      ap.u[3] = hh ? l3 : f1;
      const int lkb = lkh + kk2 * 16 + 8 * hh;
      for (int dt = 0; dt < 2; ++dt) {
        bf16x8 bv = *(const bf16x8*)&sm.a.Vs[dt * 32 + l31][lkb];
        oacc[dt] = __builtin_amdgcn_mfma_f32_32x32x16_bf16(ap.v, bv, oacc[dt], 0, 0, 0);
      }
    }
  }

  float rtot = rsum + __shfl_xor(rsum, 32);
  __syncthreads();
  if (half == 1) {
    rs1[wbase + l31] = rtot;
    for (int r = 0; r < 16; ++r) {
      int row = (r & 3) + 8 * (r >> 2) + 4 * hh;
      for (int dt = 0; dt < 2; ++dt)
        sm.Oe[wbase + row][dt * 32 + l31] = oacc[dt][r];
    }
  }
  __syncthreads();
  if (half == 0) {
    float tot = rtot + rs1[wbase + l31];
    rs1[wbase + l31] = 1.0f / tot;
    float inv[16];
    for (int r = 0; r < 16; ++r) {
      int row = (r & 3) + 8 * (r >> 2) + 4 * hh;
      inv[r] = rs1[wbase + row];
    }
    for (int r = 0; r < 16; ++r) {
      int row = (r & 3) + 8 * (r >> 2) + 4 * hh;
      for (int dt = 0; dt < 2; ++dt) {
        int col = dt * 32 + l31;
        sm.Oe[wbase + row][col] = (oacc[dt][r] + sm.Oe[wbase + row][col]) * inv[r];
      }
    }
  }
  __syncthreads();
  float* op = out + hoff + q0;
  for (int i = 0; i < 16; ++i) {
    int idx = tid + NTHREADS * i;
    int d   = idx >> 7;
    int lq  = idx & 127;
    op[(size_t)d * LL + lq] = sm.Oe[lq][d];
  }
}

extern "C" void kernel_launch(void* const* d_in, const int* in_sizes, int n_in,
                              void* d_out, int out_size, void* d_ws, size_t ws_size,
                              hipStream_t stream) {
  const float* q = (const float*)d_in[0];
  const float* k = (const float*)d_in[1];
  const float* v = (const float*)d_in[2];
  float* out = (float*)d_out;
  const size_t per_buf = (size_t)HEADS * DD * LL;           // elements
  const size_t need = 2 * per_buf * sizeof(bf16_t);         // 16.8 MB (K,V only)
  if (d_ws && ws_size >= need) {
    bf16_t* kt = (bf16_t*)d_ws;
    bf16_t* vb = kt + per_buf;
    prep_bf16_kv<<<dim3(LL / 64, HEADS, 2), 256, 0, stream>>>(k, v, kt, vb);
    attn_flash_bf16_v4<<<dim3((LL / TQ) * HEADS), NTHREADS, 0, stream>>>(q, kt, vb, out);
  } else {
    attn_flash_bf16<<<dim3(LL / TQ, HEADS), NTHREADS, 0, stream>>>(q, k, v, out);
  }
}

// Round 4
// 143.922 us; speedup vs baseline: 3.1528x; 3.1528x over previous
//
#include <hip/hip_runtime.h>
#include <math.h>

#define DD 64
#define LL 2048
#define HEADS 32
#define TQ 128
#define TK 64
#define NTHREADS 512
// 1/sqrt(64) * log2(e), folded into Q at staging (leaky commutes with positive scale)
#define QSCALE 0.18033688011112042f

typedef __bf16 bf16_t;
typedef __bf16 bf16x8 __attribute__((ext_vector_type(8)));
typedef float f32x16 __attribute__((ext_vector_type(16)));

// ============================================================================
// Prepass (K,V only — Q has no cross-block reuse, main kernel stages it):
//   z=0: KT[head][l][d] = k[head][d][l]   (transposed, bf16)
//   z=1: VB[head][d][l] = v[head][d][l]   (straight convert, bf16)
// ~33.5 MB read + 16.8 MB write => ~8 us memory-bound.
// ============================================================================
__global__ __launch_bounds__(256)
void prep_bf16_kv(const float* __restrict__ k, const float* __restrict__ v,
                  bf16_t* __restrict__ kt, bf16_t* __restrict__ vb) {
  __shared__ float ld[64][65];
  const int t = threadIdx.x;
  const int which = blockIdx.z;
  const int head = blockIdx.y;
  const int l0 = blockIdx.x * 64;
  const size_t hoff = (size_t)head * DD * LL;
  if (which == 1) {
    // V: no transpose; float2 read (coalesced), packed 4B bf16x2 write
    const float* src = v + hoff;
    bf16_t* dst = vb + hoff;
    const int lp = (t & 31) * 2;
    const int db = (t >> 5) * 8;
    for (int i = 0; i < 8; ++i) {
      int d = db + i;
      float2 x = *(const float2*)(src + (size_t)d * LL + l0 + lp);
      union { bf16_t b[2]; unsigned u; } pk;
      pk.b[0] = (bf16_t)x.x;
      pk.b[1] = (bf16_t)x.y;
      *(unsigned*)(dst + (size_t)d * LL + l0 + lp) = pk.u;
    }
  } else {
    // K: 64x64 tile transpose through LDS (pad 65: conflict-free)
    const float* src = k + hoff;
    bf16_t* dst = kt + hoff;
    const int l = t & 63;
    const int db = (t >> 6) * 16;
    for (int i = 0; i < 16; ++i) {
      int d = db + i;
      ld[l][d] = src[(size_t)d * LL + l0 + l];  // coalesced along l
    }
    __syncthreads();
    const int dp = (t & 31) * 2;
    const int lb = (t >> 5) * 8;
    for (int i = 0; i < 8; ++i) {
      int lw = lb + i;
      union { bf16_t b[2]; unsigned u; } pk;
      pk.b[0] = (bf16_t)ld[lw][dp];
      pk.b[1] = (bf16_t)ld[lw][dp + 1];
      *(unsigned*)(dst + (size_t)(l0 + lw) * DD + dp) = pk.u;  // coalesced along d
    }
  }
}

// ============================================================================
// Main kernel v5 == v4 structure with the spill bug fixed:
//  - __launch_bounds__(512, 4): compiler allocates ~60 VGPRs naturally (v2
//    measured 56). 60 <= 64 still allows 32 waves/CU at runtime; forcing 8
//    waves/EU (round 3) capped VGPR=32 and spilled ~950 MB to scratch.
//  - Qs UNIONED into Ks double-buffer => LDS 37.4 KB => 4 blocks/CU possible.
//  - XCD-aware 1D grid: bid%8 == head%8 => one head's q-tiles share an XCD;
//    4 heads x 512 KB K/V = 2 MB resident per XCD L2.
//  - Q staged from fp32 in-kernel (prepass is K/V only).
//  - rsum split into 4 accumulators (no serial 16-deep fp-add chain).
// ============================================================================
struct __align__(16) SMemA4 {
  union {
    bf16_t Qs[TQ][72];       // [lq][d] pre-scaled bf16 (dead after bq hoist)
    bf16_t Ks[2][TK][72];    // double-buffered [lk][d]
  } qk;
  bf16_t Vs[2][DD][72];      // double-buffered [d][lk]
};
union __align__(16) SMemU4 {
  SMemA4 a;
  float Oe[TQ][65];          // epilogue combine/transpose buffer (33.3 KB)
};

__global__ __launch_bounds__(NTHREADS, 4)
void attn_flash_bf16_v5(const float* __restrict__ q, const bf16_t* __restrict__ kt,
                        const bf16_t* __restrict__ vb, float* __restrict__ out) {
  __shared__ SMemU4 sm;
  __shared__ float rs1[TQ];
  const int tid  = threadIdx.x;
  const int w    = tid >> 6;        // wave 0..7
  const int lane = tid & 63;
  const int l31  = lane & 31;
  const int hh   = lane >> 5;       // half of wave
  const int strip = w & 3;          // lq strip 0..3
  const int half  = w >> 2;         // lk half 0/1
  const int wbase = strip * 32;
  const int lkh   = half * 32;
  // ---- XCD-aware decode: bid%8 pins head%8 => per-XCD L2-resident K/V ----
  const int bid  = blockIdx.x;
  const int j    = bid >> 3;
  const int head = (bid & 7) + 8 * (j >> 4);
  const int q0   = (j & 15) * TQ;
  const size_t hoff = (size_t)head * DD * LL;
  const float*  qp = q  + hoff;
  const bf16_t* kp = kt + hoff;
  const bf16_t* vp = vb + hoff;

  // staging coords: K transpose rows + V natural rows, 16B per thread each
  const int srow = tid >> 3;        // 0..63 (lk for K, d for V)
  const int scol = (tid & 7) * 8;

  // ---- prefetch tile 0 (in flight under Q staging) ----
  bf16x8 kreg = *(const bf16x8*)(kp + (size_t)srow * DD + scol);
  bf16x8 vreg = *(const bf16x8*)(vp + (size_t)srow * LL + scol);

  // ---- stage Q transposed from fp32: lanes along lq => coalesced 512B lines ----
  {
    int lq  = tid & 127;
    int d0q = (tid >> 7) * 16;
    const float* src = qp + q0 + lq;
    for (int g = 0; g < 2; ++g) {
      bf16x8 pk;
      for (int jj = 0; jj < 8; ++jj)
        pk[jj] = (bf16_t)(src[(size_t)(d0q + g * 8 + jj) * LL] * QSCALE);
      *(bf16x8*)&sm.a.qk.Qs[lq][d0q + g * 8] = pk;
    }
  }

  __syncthreads();   // Q staged
  bf16x8 bq[4];
  for (int kk = 0; kk < 4; ++kk)
    bq[kk] = *(const bf16x8*)&sm.a.qk.Qs[wbase + l31][kk * 16 + 8 * hh];
  __syncthreads();   // ALL waves done reading Qs; aliased Ks writes now safe

  f32x16 oacc[2];
  for (int dt = 0; dt < 2; ++dt)
    for (int r = 0; r < 16; ++r) oacc[dt][r] = 0.f;
  float rsl[4];
  for (int i = 0; i < 4; ++i) rsl[i] = 0.f;

  for (int t = 0; t < LL / TK; ++t) {
    const int cur = t & 1;
    // ---- commit prefetched tile into buffer `cur` (race-free single barrier:
    //      prior readers of buf[cur] were at iter t-2, separated by t-1 barrier) ----
    *(bf16x8*)&sm.a.qk.Ks[cur][srow][scol] = kreg;
    *(bf16x8*)&sm.a.Vs[cur][srow][scol]    = vreg;
    __syncthreads();

    // ---- issue prefetch for tile t+1 (in flight during compute) ----
    if (t + 1 < LL / TK) {
      const int lk0n = (t + 1) * TK;
      kreg = *(const bf16x8*)(kp + (size_t)(lk0n + srow) * DD + scol);
      vreg = *(const bf16x8*)(vp + (size_t)srow * LL + lk0n + scol);
    }

    // ---- S^T = K^T Q over this wave's lk half: C col=lq(lane), rows=lk(regs) ----
    f32x16 st;
    for (int r = 0; r < 16; ++r) st[r] = 0.f;
    __builtin_amdgcn_s_setprio(1);
    for (int kk = 0; kk < 4; ++kk) {
      bf16x8 ak = *(const bf16x8*)&sm.a.qk.Ks[cur][lkh + l31][kk * 16 + 8 * hh];
      st = __builtin_amdgcn_mfma_f32_32x32x16_bf16(ak, bq[kk], st, 0, 0, 0);
    }
    __builtin_amdgcn_s_setprio(0);

    // ---- leaky + exp2 in registers (4-way split sum: no serial add chain) ----
    unsigned pb[8];
#pragma unroll
    for (int r = 0; r < 16; ++r) {
      float s = st[r];
      s = fmaxf(s, 0.01f * s);
      float p = __builtin_amdgcn_exp2f(s);
      rsl[r & 3] += p;
      st[r] = p;
    }
    for (int qq = 0; qq < 8; ++qq) {
      union { bf16_t b[2]; unsigned u; } pk;
      pk.b[0] = (bf16_t)st[2 * qq];
      pk.b[1] = (bf16_t)st[2 * qq + 1];
      pb[qq] = pk.u;
    }

    // ---- PV over this wave's lk half: one cross-half exchange ----
    for (int kk2 = 0; kk2 < 2; ++kk2) {
      unsigned l0 = pb[4 * kk2 + 0], l1 = pb[4 * kk2 + 1];
      unsigned l2 = pb[4 * kk2 + 2], l3 = pb[4 * kk2 + 3];
      unsigned s0 = hh ? l0 : l2;
      unsigned s1 = hh ? l1 : l3;
      unsigned f0 = (unsigned)__shfl_xor((int)s0, 32);
      unsigned f1 = (unsigned)__shfl_xor((int)s1, 32);
      union { unsigned u[4]; bf16x8 v; } ap;
      ap.u[0] = hh ? f0 : l0;
      ap.u[1] = hh ? f1 : l1;
      ap.u[2] = hh ? l2 : f0;
      ap.u[3] = hh ? l3 : f1;
      const int lkb = lkh + kk2 * 16 + 8 * hh;
      __builtin_amdgcn_s_setprio(1);
      for (int dt = 0; dt < 2; ++dt) {
        bf16x8 bv = *(const bf16x8*)&sm.a.Vs[cur][dt * 32 + l31][lkb];
        oacc[dt] = __builtin_amdgcn_mfma_f32_32x32x16_bf16(ap.v, bv, oacc[dt], 0, 0, 0);
      }
      __builtin_amdgcn_s_setprio(0);
    }
  }

  // ---- epilogue: combine lk-half pairs, normalize, transpose, store ----
  float rsum = (rsl[0] + rsl[1]) + (rsl[2] + rsl[3]);
  float rtot = rsum + __shfl_xor(rsum, 32);   // both hh row-groups of this wave
  __syncthreads();                            // all compute LDS reads done; union safe
  if (half == 1) {
    rs1[wbase + l31] = rtot;
    for (int r = 0; r < 16; ++r) {
      int row = (r & 3) + 8 * (r >> 2) + 4 * hh;
      for (int dt = 0; dt < 2; ++dt)
        sm.Oe[wbase + row][dt * 32 + l31] = oacc[dt][r];
    }
  }
  __syncthreads();
  if (half == 0) {
    float tot = rtot + rs1[wbase + l31];
    rs1[wbase + l31] = 1.0f / tot;            // same-lane read-then-write: safe in-wave
    float inv[16];
    for (int r = 0; r < 16; ++r) {
      int row = (r & 3) + 8 * (r >> 2) + 4 * hh;
      inv[r] = rs1[wbase + row];              // in-wave broadcast reads
    }
    for (int r = 0; r < 16; ++r) {
      int row = (r & 3) + 8 * (r >> 2) + 4 * hh;
      for (int dt = 0; dt < 2; ++dt) {
        int col = dt * 32 + l31;
        sm.Oe[wbase + row][col] = (oacc[dt][r] + sm.Oe[wbase + row][col]) * inv[r];
      }
    }
  }
  __syncthreads();
  float* op = out + hoff + q0;
  for (int i = 0; i < 16; ++i) {
    int idx = tid + NTHREADS * i;  // 0..8191
    int d   = idx >> 7;
    int lq  = idx & 127;
    op[(size_t)d * LL + lq] = sm.Oe[lq][d];   // coalesced: lanes -> consecutive lq
  }
}

// ============================================================================
// Fallback: the original harness-verified fp32-input kernel, used only if
// ws_size is too small for the bf16 prepass buffers.
// ============================================================================
struct __align__(16) SMemA {
  bf16_t Qs[TQ][72];
  bf16_t Ks[TK][72];
  bf16_t Vs[DD][72];
};
union __align__(16) SMemU {
  SMemA a;
  float Oe[TQ][65];
};

__global__ __launch_bounds__(NTHREADS, 4)
void attn_flash_bf16(const float* __restrict__ q, const float* __restrict__ k,
                     const float* __restrict__ v, float* __restrict__ out) {
  __shared__ SMemU sm;
  __shared__ float rs1[TQ];
  const int tid  = threadIdx.x;
  const int w    = tid >> 6;
  const int lane = tid & 63;
  const int l31  = lane & 31;
  const int hh   = lane >> 5;
  const int strip = w & 3;
  const int half  = w >> 2;
  const int wbase = strip * 32;
  const int lkh   = half * 32;
  const int head = blockIdx.y;
  const int q0   = blockIdx.x * TQ;
  const size_t hoff = (size_t)head * DD * LL;
  const float* qp = q + hoff;
  const float* kp = k + hoff;
  const float* vp = v + hoff;

  {
    int lq  = tid & 127;
    int d0q = (tid >> 7) * 16;
    const float* src = qp + q0 + lq;
    for (int g = 0; g < 2; ++g) {
      bf16x8 pk;
      for (int jj = 0; jj < 8; ++jj)
        pk[jj] = (bf16_t)(src[(size_t)(d0q + g * 8 + jj) * LL] * QSCALE);
      *(bf16x8*)&sm.a.Qs[lq][d0q + g * 8] = pk;
    }
  }

  const int klk = tid & 63;
  const int kd0 = (tid >> 6) * 8;
  const int vd  = tid >> 3;
  const int vc8 = (tid & 7) * 8;

  float  kreg[8];
  float4 vreg[2];
  {
    const float* ks = kp + klk;
    for (int jj = 0; jj < 8; ++jj) kreg[jj] = ks[(size_t)(kd0 + jj) * LL];
    vreg[0] = *(const float4*)(vp + (size_t)vd * LL + vc8);
    vreg[1] = *(const float4*)(vp + (size_t)vd * LL + vc8 + 4);
  }

  __syncthreads();
  bf16x8 bq[4];
  for (int kk = 0; kk < 4; ++kk)
    bq[kk] = *(const bf16x8*)&sm.a.Qs[wbase + l31][kk * 16 + 8 * hh];

  f32x16 oacc[2];
  for (int dt = 0; dt < 2; ++dt)
    for (int r = 0; r < 16; ++r) oacc[dt][r] = 0.f;
  float rsum = 0.f;

  for (int t = 0; t < LL / TK; ++t) {
    __syncthreads();
    {
      bf16x8 pk;
      for (int jj = 0; jj < 8; ++jj) pk[jj] = (bf16_t)kreg[jj];
      *(bf16x8*)&sm.a.Ks[klk][kd0] = pk;
      bf16x8 pv;
      pv[0] = (bf16_t)vreg[0].x; pv[1] = (bf16_t)vreg[0].y;
      pv[2] = (bf16_t)vreg[0].z; pv[3] = (bf16_t)vreg[0].w;
      pv[4] = (bf16_t)vreg[1].x; pv[5] = (bf16_t)vreg[1].y;
      pv[6] = (bf16_t)vreg[1].z; pv[7] = (bf16_t)vreg[1].w;
      *(bf16x8*)&sm.a.Vs[vd][vc8] = pv;
    }
    __syncthreads();

    if (t + 1 < LL / TK) {
      const int lk0n = (t + 1) * TK;
      const float* ks = kp + lk0n + klk;
      for (int jj = 0; jj < 8; ++jj) kreg[jj] = ks[(size_t)(kd0 + jj) * LL];
      vreg[0] = *(const float4*)(vp + (size_t)vd * LL + lk0n + vc8);
      vreg[1] = *(const float4*)(vp + (size_t)vd * LL + lk0n + vc8 + 4);
    }

    f32x16 st;
    for (int r = 0; r < 16; ++r) st[r] = 0.f;
    for (int kk = 0; kk < 4; ++kk) {
      bf16x8 ak = *(const bf16x8*)&sm.a.Ks[lkh + l31][kk * 16 + 8 * hh];
      st = __builtin_amdgcn_mfma_f32_32x32x16_bf16(ak, bq[kk], st, 0, 0, 0);
    }

    unsigned pb[8];
    for (int r = 0; r < 16; ++r) {
      float s = st[r];
      s = fmaxf(s, 0.01f * s);
      float p = __builtin_amdgcn_exp2f(s);
      rsum += p;
      st[r] = p;
    }
    for (int qq = 0; qq < 8; ++qq) {
      union { bf16_t b[2]; unsigned u; } pk;
      pk.b[0] = (bf16_t)st[2 * qq];
      pk.b[1] = (bf16_t)st[2 * qq + 1];
      pb[qq] = pk.u;
    }

    for (int kk2 = 0; kk2 < 2; ++kk2) {
      unsigned l0 = pb[4 * kk2 + 0], l1 = pb[4 * kk2 + 1];
      unsigned l2 = pb[4 * kk2 + 2], l3 = pb[4 * kk2 + 3];
      unsigned s0 = hh ? l0 : l2;
      unsigned s1 = hh ? l1 : l3;
      unsigned f0 = (unsigned)__shfl_xor((int)s0, 32);
      unsigned f1 = (unsigned)__shfl_xor((int)s1, 32);
      union { unsigned u[4]; bf16x8 v; } ap;
      ap.u[0] = hh ? f0 : l0;
      ap.u[1] = hh ? f1 : l1;
      ap.u[2] = hh ? l2 : f0;
      ap.u[3] = hh ? l3 : f1;
      const int lkb = lkh + kk2 * 16 + 8 * hh;
      for (int dt = 0; dt < 2; ++dt) {
        bf16x8 bv = *(const bf16x8*)&sm.a.Vs[dt * 32 + l31][lkb];
        oacc[dt] = __builtin_amdgcn_mfma_f32_32x32x16_bf16(ap.v, bv, oacc[dt], 0, 0, 0);
      }
    }
  }

  float rtot = rsum + __shfl_xor(rsum, 32);
  __syncthreads();
  if (half == 1) {
    rs1[wbase + l31] = rtot;
    for (int r = 0; r < 16; ++r) {
      int row = (r & 3) + 8 * (r >> 2) + 4 * hh;
      for (int dt = 0; dt < 2; ++dt)
        sm.Oe[wbase + row][dt * 32 + l31] = oacc[dt][r];
    }
  }
  __syncthreads();
  if (half == 0) {
    float tot = rtot + rs1[wbase + l31];
    rs1[wbase + l31] = 1.0f / tot;
    float inv[16];
    for (int r = 0; r < 16; ++r) {
      int row = (r & 3) + 8 * (r >> 2) + 4 * hh;
      inv[r] = rs1[wbase + row];
    }
    for (int r = 0; r < 16; ++r) {
      int row = (r & 3) + 8 * (r >> 2) + 4 * hh;
      for (int dt = 0; dt < 2; ++dt) {
        int col = dt * 32 + l31;
        sm.Oe[wbase + row][col] = (oacc[dt][r] + sm.Oe[wbase + row][col]) * inv[r];
      }
    }
  }
  __syncthreads();
  float* op = out + hoff + q0;
  for (int i = 0; i < 16; ++i) {
    int idx = tid + NTHREADS * i;
    int d   = idx >> 7;
    int lq  = idx & 127;
    op[(size_t)d * LL + lq] = sm.Oe[lq][d];
  }
}

extern "C" void kernel_launch(void* const* d_in, const int* in_sizes, int n_in,
                              void* d_out, int out_size, void* d_ws, size_t ws_size,
                              hipStream_t stream) {
  const float* q = (const float*)d_in[0];
  const float* k = (const float*)d_in[1];
  const float* v = (const float*)d_in[2];
  float* out = (float*)d_out;
  const size_t per_buf = (size_t)HEADS * DD * LL;           // elements
  const size_t need = 2 * per_buf * sizeof(bf16_t);         // 16.8 MB (K,V only)
  if (d_ws && ws_size >= need) {
    bf16_t* kt = (bf16_t*)d_ws;
    bf16_t* vb = kt + per_buf;
    prep_bf16_kv<<<dim3(LL / 64, HEADS, 2), 256, 0, stream>>>(k, v, kt, vb);
    attn_flash_bf16_v5<<<dim3((LL / TQ) * HEADS), NTHREADS, 0, stream>>>(q, kt, vb, out);
  } else {
    attn_flash_bf16<<<dim3(LL / TQ, HEADS), NTHREADS, 0, stream>>>(q, k, v, out);
  }
}